// Round 6
// baseline (307.743 us; speedup 1.0000x reference)
//
#include <hip/hip_runtime.h>

// CRF forward-score + gold-score, MI355X (gfx950).
//
// R6: matvec in inline asm with hard register constraints. R4/R5 showed
// VGPR_Count=48 — the allocator SPILLED the 64-element E row to scratch
// (reload 64 dw/step from L1/L2; invisible in FETCH_SIZE) despite the
// ",1" launch bound and a "+v" touch-pin (a pin blocks remat, not
// allocation). Here every e[j] is a "v" asm operand in every step, so
// keeping E live (~90 regs vs 512 budget) is the only sane allocation.
// The asm also fixes the schedule: 8 readlanes batched ahead of their 8
// v_fmac_f32 (hazard gaps self-covered), accumulators rotated so no FMA
// chain ever stalls (each acc touched once per 16-instr block).
//
// Recurrence (exp-domain, fresh power-of-two normalization):
//   p_t ~ beta_t scaled; alpha_t[i] = log(p_t[i]) + esum_t*ln2
//   z[i]  = sum_j E[i][j]*p[j]   (E=exp(T) in VGPRs; p broadcast via
//                                 v_readlane -> SGPR -> fmac src0)
//   e     = exponent(partial a0) (readlane inside last asm block — partial
//           sum is a valid normalizer: esum records the ACTUAL e applied,
//           fresh-per-step => memoryless => stable; a0>0 strictly for t>=2)
//   p_t   = q * (exp(u_t) * 2^-e),  esum += e  (int, exact)
// Step t=1 collapses: beta_0 one-hot at START => p_1 = e[62]*exp(u_1),
// loop runs t=2..511 (510 = 6*85; feat ring depth 6, indices const-fold).
// Sentinels (-10000) underflow to exact 0 in E (row START dies, col STOP
// never contributes), matching the fp32 reference's own underflow.
//
// One wave per batch: 1024 blocks x 64 threads -> 1 wave/SIMD machine-wide.

#define BB 1024
#define TT 512
#define KK 64
#define START_TAG 62

// ---- matvec blocks: 8 readlanes then 8 fmacs (accumulator-rotated) ----
// v_fmac_f32 dst, src0(SGPR), src1(VGPR) — one scalar operand is legal.
// Lane index literals: "k*8+m" folds in the assembler (inline const 0..63).

#define MV_BLOCK(k)                                                          \
  asm volatile(                                                              \
      "v_readlane_b32 %[t0], %[vp], " #k "*8+0\n\t"                          \
      "v_readlane_b32 %[t1], %[vp], " #k "*8+1\n\t"                          \
      "v_readlane_b32 %[t2], %[vp], " #k "*8+2\n\t"                          \
      "v_readlane_b32 %[t3], %[vp], " #k "*8+3\n\t"                          \
      "v_readlane_b32 %[t4], %[vp], " #k "*8+4\n\t"                          \
      "v_readlane_b32 %[t5], %[vp], " #k "*8+5\n\t"                          \
      "v_readlane_b32 %[t6], %[vp], " #k "*8+6\n\t"                          \
      "v_readlane_b32 %[t7], %[vp], " #k "*8+7\n\t"                          \
      "v_fmac_f32 %[a0], %[t0], %[e0]\n\t"                                   \
      "v_fmac_f32 %[a1], %[t1], %[e1]\n\t"                                   \
      "v_fmac_f32 %[a2], %[t2], %[e2]\n\t"                                   \
      "v_fmac_f32 %[a3], %[t3], %[e3]\n\t"                                   \
      "v_fmac_f32 %[a4], %[t4], %[e4]\n\t"                                   \
      "v_fmac_f32 %[a5], %[t5], %[e5]\n\t"                                   \
      "v_fmac_f32 %[a6], %[t6], %[e6]\n\t"                                   \
      "v_fmac_f32 %[a7], %[t7], %[e7]\n\t"                                   \
      : [a0] "+v"(a0), [a1] "+v"(a1), [a2] "+v"(a2), [a3] "+v"(a3),          \
        [a4] "+v"(a4), [a5] "+v"(a5), [a6] "+v"(a6), [a7] "+v"(a7),          \
        [t0] "=&s"(t0), [t1] "=&s"(t1), [t2] "=&s"(t2), [t3] "=&s"(t3),      \
        [t4] "=&s"(t4), [t5] "=&s"(t5), [t6] "=&s"(t6), [t7] "=&s"(t7)       \
      : [vp] "v"(p),                                                         \
        [e0] "v"(e[(k)*8 + 0]), [e1] "v"(e[(k)*8 + 1]),                      \
        [e2] "v"(e[(k)*8 + 2]), [e3] "v"(e[(k)*8 + 3]),                      \
        [e4] "v"(e[(k)*8 + 4]), [e5] "v"(e[(k)*8 + 5]),                      \
        [e6] "v"(e[(k)*8 + 6]), [e7] "v"(e[(k)*8 + 7]))

// Block 0: v_mul (first touch — no acc init needed), outputs early-clobber.
#define MV_BLOCK0()                                                          \
  asm volatile(                                                              \
      "v_readlane_b32 %[t0], %[vp], 0\n\t"                                   \
      "v_readlane_b32 %[t1], %[vp], 1\n\t"                                   \
      "v_readlane_b32 %[t2], %[vp], 2\n\t"                                   \
      "v_readlane_b32 %[t3], %[vp], 3\n\t"                                   \
      "v_readlane_b32 %[t4], %[vp], 4\n\t"                                   \
      "v_readlane_b32 %[t5], %[vp], 5\n\t"                                   \
      "v_readlane_b32 %[t6], %[vp], 6\n\t"                                   \
      "v_readlane_b32 %[t7], %[vp], 7\n\t"                                   \
      "v_mul_f32 %[a0], %[t0], %[e0]\n\t"                                    \
      "v_mul_f32 %[a1], %[t1], %[e1]\n\t"                                    \
      "v_mul_f32 %[a2], %[t2], %[e2]\n\t"                                    \
      "v_mul_f32 %[a3], %[t3], %[e3]\n\t"                                    \
      "v_mul_f32 %[a4], %[t4], %[e4]\n\t"                                    \
      "v_mul_f32 %[a5], %[t5], %[e5]\n\t"                                    \
      "v_mul_f32 %[a6], %[t6], %[e6]\n\t"                                    \
      "v_mul_f32 %[a7], %[t7], %[e7]\n\t"                                    \
      : [a0] "=&v"(a0), [a1] "=&v"(a1), [a2] "=&v"(a2), [a3] "=&v"(a3),      \
        [a4] "=&v"(a4), [a5] "=&v"(a5), [a6] "=&v"(a6), [a7] "=&v"(a7),      \
        [t0] "=&s"(t0), [t1] "=&s"(t1), [t2] "=&s"(t2), [t3] "=&s"(t3),      \
        [t4] "=&s"(t4), [t5] "=&s"(t5), [t6] "=&s"(t6), [t7] "=&s"(t7)       \
      : [vp] "v"(p),                                                         \
        [e0] "v"(e[0]), [e1] "v"(e[1]), [e2] "v"(e[2]), [e3] "v"(e[3]),      \
        [e4] "v"(e[4]), [e5] "v"(e[5]), [e6] "v"(e[6]), [e7] "v"(e[7]))

// Block 7: after the a0 fmac, readlane a0 lane0 -> zb (partial-sum exponent
// source, ready ~15 instrs before block end; overlaps SALU + fs mul).
#define MV_BLOCK7()                                                          \
  asm volatile(                                                              \
      "v_readlane_b32 %[t0], %[vp], 56\n\t"                                  \
      "v_readlane_b32 %[t1], %[vp], 57\n\t"                                  \
      "v_readlane_b32 %[t2], %[vp], 58\n\t"                                  \
      "v_readlane_b32 %[t3], %[vp], 59\n\t"                                  \
      "v_readlane_b32 %[t4], %[vp], 60\n\t"                                  \
      "v_readlane_b32 %[t5], %[vp], 61\n\t"                                  \
      "v_readlane_b32 %[t6], %[vp], 62\n\t"                                  \
      "v_readlane_b32 %[t7], %[vp], 63\n\t"                                  \
      "v_fmac_f32 %[a0], %[t0], %[e0]\n\t"                                   \
      "v_readlane_b32 %[zb], %[a0], 0\n\t"                                   \
      "v_fmac_f32 %[a1], %[t1], %[e1]\n\t"                                   \
      "v_fmac_f32 %[a2], %[t2], %[e2]\n\t"                                   \
      "v_fmac_f32 %[a3], %[t3], %[e3]\n\t"                                   \
      "v_fmac_f32 %[a4], %[t4], %[e4]\n\t"                                   \
      "v_fmac_f32 %[a5], %[t5], %[e5]\n\t"                                   \
      "v_fmac_f32 %[a6], %[t6], %[e6]\n\t"                                   \
      "v_fmac_f32 %[a7], %[t7], %[e7]\n\t"                                   \
      : [a0] "+v"(a0), [a1] "+v"(a1), [a2] "+v"(a2), [a3] "+v"(a3),          \
        [a4] "+v"(a4), [a5] "+v"(a5), [a6] "+v"(a6), [a7] "+v"(a7),          \
        [t0] "=&s"(t0), [t1] "=&s"(t1), [t2] "=&s"(t2), [t3] "=&s"(t3),      \
        [t4] "=&s"(t4), [t5] "=&s"(t5), [t6] "=&s"(t6), [t7] "=&s"(t7),      \
        [zb] "=&s"(zb)                                                       \
      : [vp] "v"(p),                                                         \
        [e0] "v"(e[56]), [e1] "v"(e[57]), [e2] "v"(e[58]), [e3] "v"(e[59]),  \
        [e4] "v"(e[60]), [e5] "v"(e[61]), [e6] "v"(e[62]), [e7] "v"(e[63]))

__global__ __launch_bounds__(64, 1) void crf_forward_kernel(
    const float* __restrict__ feats,   // [B, T, K]
    const int*   __restrict__ tags,    // [B, T]
    const float* __restrict__ trans,   // [K, K]  trans[i*K+j] = score j -> i
    float*       __restrict__ diff)    // [B]  forward - gold
{
  const int lane = threadIdx.x;        // 0..63 == tag index
  const int b    = blockIdx.x;

  // ---- E row: e[j] = exp(trans[lane][j]) ----
  float e[KK];
  {
    const float4* trow = (const float4*)(trans + lane * KK);
    #pragma unroll
    for (int jc = 0; jc < 16; ++jc) {
      float4 tv = trow[jc];
      e[4 * jc + 0] = __expf(tv.x);
      e[4 * jc + 1] = __expf(tv.y);
      e[4 * jc + 2] = __expf(tv.z);
      e[4 * jc + 3] = __expf(tv.w);
    }
  }
  #pragma unroll
  for (int j = 0; j < KK; ++j) asm volatile("" : "+v"(e[j]));  // no remat

  const float* fb = feats + (size_t)b * TT * KK + lane;

  // t=1 collapses: beta_0 one-hot at START => p_1 = E[lane][62]*exp(u_1).
  float u1 = fb[(size_t)1 * KK];
  float p  = e[62] * __expf(u1);
  int esum = 0;

  // ---- feat ring: depth 6; upf[d] holds u_{2+d}; refilled with u_{t+6} ----
  float upf[6];
  #pragma unroll
  for (int d = 0; d < 6; ++d) upf[d] = fb[(size_t)(2 + d) * KK];

  float f_cur = __expf(upf[0]);        // exp(u_2)

  for (int g = 0; g < 85; ++g) {       // t = 2..511, 510 = 6*85
    #pragma unroll
    for (int dd = 0; dd < 6; ++dd) {
      const int t = 2 + g * 6 + dd;

      // refill slot dd with u_{t+6} (consumed 5 iterations later)
      int tn = t + 6; if (tn > TT - 1) tn = TT - 1;
      float unew = fb[(size_t)tn * KK];

      float a0, a1, a2, a3, a4, a5, a6, a7;
      float t0, t1, t2, t3, t4, t5, t6, t7;
      unsigned zb;
      MV_BLOCK0();
      MV_BLOCK(1); MV_BLOCK(2); MV_BLOCK(3);
      MV_BLOCK(4); MV_BLOCK(5); MV_BLOCK(6);
      MV_BLOCK7();

      // normalization scale from partial-sum exponent (SALU, overlaps tree)
      unsigned sb = 0x7F000000u - (zb & 0x7F800000u);     // 2^-(e)
      esum += (int)((zb >> 23) & 0xFFu) - 127;
      float fs = f_cur * __uint_as_float(sb);             // exp(u_t)*2^-e

      float q = ((a0 + a1) + (a2 + a3)) + ((a4 + a5) + (a6 + a7));
      p = q * fs;

      upf[dd] = unew;
      f_cur = __expf(upf[(dd + 1) % 6]);                  // exp(u_{t+1})
    }
  }

  // forward score = log(sum_j p) + esum*ln2
  float bs = p;
  #pragma unroll
  for (int off = 32; off; off >>= 1) bs += __shfl_xor(bs, off);
  float fwd = __logf(bs) + (float)esum * 0.6931471805599453f;

  // ---- gold path score ----
  const int* tg = tags + b * TT;
  float gs = 0.0f;
  for (int tt = 1 + lane; tt < TT; tt += 64) {
    int tc = tg[tt];
    int tp = tg[tt - 1];
    gs += trans[tc * KK + tp]
        + feats[(size_t)b * TT * KK + (size_t)tt * KK + tc];
  }
  #pragma unroll
  for (int off = 32; off; off >>= 1) gs += __shfl_xor(gs, off);

  if (lane == 0) diff[b] = fwd - gs;
}

__global__ __launch_bounds__(1024) void reduce_mean_kernel(
    const float* __restrict__ diff, float* __restrict__ out)
{
  __shared__ float part[16];
  const int tid = threadIdx.x;
  float v = diff[tid];
  #pragma unroll
  for (int off = 32; off; off >>= 1) v += __shfl_xor(v, off);
  if ((tid & 63) == 0) part[tid >> 6] = v;
  __syncthreads();
  if (tid < 16) {
    float s = part[tid];
    #pragma unroll
    for (int off = 8; off; off >>= 1) s += __shfl_xor(s, off);
    if (tid == 0) out[0] = s * (1.0f / 1024.0f);
  }
}

extern "C" void kernel_launch(void* const* d_in, const int* in_sizes, int n_in,
                              void* d_out, int out_size, void* d_ws, size_t ws_size,
                              hipStream_t stream) {
  const float* feats = (const float*)d_in[0];
  const int*   tags  = (const int*)d_in[1];
  const float* trans = (const float*)d_in[2];
  float* out  = (float*)d_out;
  float* diff = (float*)d_ws;   // 1024 floats of scratch

  crf_forward_kernel<<<dim3(BB), dim3(64), 0, stream>>>(feats, tags, trans, diff);
  reduce_mean_kernel<<<dim3(1), dim3(1024), 0, stream>>>(diff, out);
}

// Round 7
// 295.358 us; speedup vs baseline: 1.0419x; 1.0419x over previous
//
#include <hip/hip_runtime.h>

// CRF forward-score + gold-score, MI355X (gfx950).
//
// R7: ENTIRE hot loop in one asm volatile block with hand-assigned registers.
// R1/R3-R6 evidence: the RA caps this kernel at 48-68 VGPRs regardless of
// __launch_bounds__(64,1), touch-pins, or per-use asm operands — the
// 64-element E row never stays resident (scratch/AGPR shuffling ~64 extra
// ops/step). Hand allocation: E=exp(trans-row) in v32..v95, accs v10..v17,
// feat ring v18..v23, f_cur/f_next v24/v25, p(beta) v26, offset v27,
// fs/scratch v28, clamped addr v29. Readlane targets alternate SGPR banks
// s40-47/s48-55 (write->read distance 8 covers SGPR-RAW hazard; pattern
// HW-validated in R6). Declared clobbers force VGPR_Count >= 96.
//
// Math identical to R6 (absmax was 0): exp-domain recurrence, fresh pow2
// normalizer from partial accumulator a0's lane-0 exponent, esum in int
// (bias -127*510 folded out in C), identical tree-sum order.
//   z[i] = sum_j E[i][j]*p[j]  (p broadcast: v_readlane -> SGPR -> fmac src0)
//   p'   = z * (exp(u_t) * 2^-e),  esum += e'   (e' = biased exponent of a0[0])
// t=1 collapses (beta_0 one-hot at START): p_1 = E[lane][62]*exp(u_1).
// Loop t=2..511: 85 iterations x 6 unrolled bodies (ring indices static).
// v_exp_f32 is 2^x: exp(x) = v_mul by log2e (s61) + v_exp.
// Feat loads: saddr form (SGPR base + 32-bit VGPR byte offset), +256/step,
// v_min-clamped to t=511 (tail loads redundant, never consumed).
// vmcnt(5) guard: slot d+1's load is always exactly 6 loads old when read.
//
// One wave per batch: 1024 blocks x 64 threads -> 1 wave/SIMD machine-wide.

#define BB 1024
#define TT 512
#define KK 64
#define START_TAG 62

// ---- asm text helpers ----
#define RL(S, L)     "v_readlane_b32 s" #S ", v26, " #L "\n\t"
#define FM(A, S, E)  "v_fmac_f32 v" #A ", s" #S ", v" #E "\n\t"
#define ML(A, S, E)  "v_mul_f32 v" #A ", s" #S ", v" #E "\n\t"
#define EM(R)        "v_mul_f32 v" #R ", s61, v" #R "\n\t"
#define EX(R)        "v_exp_f32 v" #R ", v" #R "\n\t"
#define EM8(a,b,c,d,e,f,g,h) EM(a) EM(b) EM(c) EM(d) EM(e) EM(f) EM(g) EM(h)
#define EX8(a,b,c,d,e,f,g,h) EX(a) EX(b) EX(c) EX(d) EX(e) EX(f) EX(g) EX(h)

// 64-term matvec: 8 blocks of (8 readlanes, 8 fmacs), accs rotated, banks
// alternated. Block 7 readlanes the finished a0 (v10) for the normalizer.
#define MATVEC \
  RL(40,0)  RL(41,1)  RL(42,2)  RL(43,3)  RL(44,4)  RL(45,5)  RL(46,6)  RL(47,7)  \
  ML(10,40,32) ML(11,41,33) ML(12,42,34) ML(13,43,35) ML(14,44,36) ML(15,45,37) ML(16,46,38) ML(17,47,39) \
  RL(48,8)  RL(49,9)  RL(50,10) RL(51,11) RL(52,12) RL(53,13) RL(54,14) RL(55,15) \
  FM(10,48,40) FM(11,49,41) FM(12,50,42) FM(13,51,43) FM(14,52,44) FM(15,53,45) FM(16,54,46) FM(17,55,47) \
  RL(40,16) RL(41,17) RL(42,18) RL(43,19) RL(44,20) RL(45,21) RL(46,22) RL(47,23) \
  FM(10,40,48) FM(11,41,49) FM(12,42,50) FM(13,43,51) FM(14,44,52) FM(15,45,53) FM(16,46,54) FM(17,47,55) \
  RL(48,24) RL(49,25) RL(50,26) RL(51,27) RL(52,28) RL(53,29) RL(54,30) RL(55,31) \
  FM(10,48,56) FM(11,49,57) FM(12,50,58) FM(13,51,59) FM(14,52,60) FM(15,53,61) FM(16,54,62) FM(17,55,63) \
  RL(40,32) RL(41,33) RL(42,34) RL(43,35) RL(44,36) RL(45,37) RL(46,38) RL(47,39) \
  FM(10,40,64) FM(11,41,65) FM(12,42,66) FM(13,43,67) FM(14,44,68) FM(15,45,69) FM(16,46,70) FM(17,47,71) \
  RL(48,40) RL(49,41) RL(50,42) RL(51,43) RL(52,44) RL(53,45) RL(54,46) RL(55,47) \
  FM(10,48,72) FM(11,49,73) FM(12,50,74) FM(13,51,75) FM(14,52,76) FM(15,53,77) FM(16,54,78) FM(17,55,79) \
  RL(40,48) RL(41,49) RL(42,50) RL(43,51) RL(44,52) RL(45,53) RL(46,54) RL(47,55) \
  FM(10,40,80) FM(11,41,81) FM(12,42,82) FM(13,43,83) FM(14,44,84) FM(15,45,85) FM(16,46,86) FM(17,47,87) \
  RL(48,56) RL(49,57) RL(50,58) RL(51,59) RL(52,60) RL(53,61) RL(54,62) RL(55,63) \
  FM(10,48,88) \
  "v_readlane_b32 s56, v10, 0\n\t" \
  FM(11,49,89) FM(12,50,90) FM(13,51,91) FM(14,52,92) FM(15,53,93) FM(16,54,94) FM(17,55,95)

// One step. LDS=ring slot reg to refill (u_{t+6}); NXT=slot holding u_{t+1};
// FC=this step's exp(u_t); FN=reg for next step's exp(u_{t+1}).
#define BODY(LDS, NXT, FC, FN) \
  "v_min_u32 v29, %[vmax], v27\n\t" \
  "global_load_dword " LDS ", v29, %[fb]\n\t" \
  "v_add_u32 v27, 0x100, v27\n\t" \
  "s_waitcnt vmcnt(5)\n\t" \
  "v_mul_f32 " FN ", s61, " NXT "\n\t" \
  "v_exp_f32 " FN ", " FN "\n\t" \
  MATVEC \
  "s_lshr_b32 s57, s56, 23\n\t" \
  "s_and_b32 s57, s57, 0xff\n\t" \
  "s_add_i32 s58, s58, s57\n\t" \
  "s_and_b32 s59, s56, 0x7f800000\n\t" \
  "s_sub_u32 s59, 0x7f000000, s59\n\t" \
  "v_add_f32 v10, v10, v11\n\t" \
  "v_add_f32 v12, v12, v13\n\t" \
  "v_add_f32 v14, v14, v15\n\t" \
  "v_add_f32 v16, v16, v17\n\t" \
  "v_mul_f32 v28, s59, " FC "\n\t" \
  "v_add_f32 v10, v10, v12\n\t" \
  "v_add_f32 v14, v14, v16\n\t" \
  "v_add_f32 v10, v10, v14\n\t" \
  "v_mul_f32 v26, v10, v28\n\t"

#define LDE(A, B, OFF) \
  "global_load_dwordx4 v[" #A ":" #B "], %[ta], off offset:" #OFF "\n\t"

__global__ __launch_bounds__(64, 1) void crf_forward_kernel(
    const float* __restrict__ feats,   // [B, T, K]
    const int*   __restrict__ tags,    // [B, T]
    const float* __restrict__ trans,   // [K, K]  trans[i*K+j] = score j -> i
    float*       __restrict__ diff)    // [B]  forward - gold
{
  const int lane = threadIdx.x;        // 0..63 == tag index
  const int b    = blockIdx.x;

  unsigned long long fb64 = (unsigned long long)(uintptr_t)feats;
  unsigned long long ta64 = (unsigned long long)(uintptr_t)(trans + lane * KK);
  unsigned voff = ((unsigned)b * (TT * KK) + (unsigned)lane) * 4u; // t=0 byte off
  unsigned vmax = voff + 511u * 256u;                              // t=511 clamp

  float p_out;
  int   esum_raw;

  asm volatile(
    // ---------------- prologue ----------------
    "s_mov_b32 s58, 0\n\t"                       // esum
    "s_mov_b32 s61, 0x3fb8aa3b\n\t"              // log2(e)
    "s_movk_i32 s60, 85\n\t"                     // loop count
    LDE(32,35,0)   LDE(36,39,16)  LDE(40,43,32)  LDE(44,47,48)
    LDE(48,51,64)  LDE(52,55,80)  LDE(56,59,96)  LDE(60,63,112)
    LDE(64,67,128) LDE(68,71,144) LDE(72,75,160) LDE(76,79,176)
    LDE(80,83,192) LDE(84,87,208) LDE(88,91,224) LDE(92,95,240)
    "v_add_u32 v27, 0x100, %[voff]\n\t"          // t=1
    "global_load_dword v28, v27, %[fb]\n\t"      // u_1
    "v_add_u32 v27, 0x100, v27\n\t"
    "global_load_dword v18, v27, %[fb]\n\t"      // u_2
    "v_add_u32 v27, 0x100, v27\n\t"
    "global_load_dword v19, v27, %[fb]\n\t"      // u_3
    "v_add_u32 v27, 0x100, v27\n\t"
    "global_load_dword v20, v27, %[fb]\n\t"      // u_4
    "v_add_u32 v27, 0x100, v27\n\t"
    "global_load_dword v21, v27, %[fb]\n\t"      // u_5
    "v_add_u32 v27, 0x100, v27\n\t"
    "global_load_dword v22, v27, %[fb]\n\t"      // u_6
    "v_add_u32 v27, 0x100, v27\n\t"
    "global_load_dword v23, v27, %[fb]\n\t"      // u_7
    "v_add_u32 v27, 0x100, v27\n\t"              // next load: t=8
    "s_waitcnt vmcnt(0)\n\t"
    // E = exp(trans_row) = 2^(trans_row * log2e), in place v32..v95
    EM8(32,33,34,35,36,37,38,39) EM8(40,41,42,43,44,45,46,47)
    EM8(48,49,50,51,52,53,54,55) EM8(56,57,58,59,60,61,62,63)
    EM8(64,65,66,67,68,69,70,71) EM8(72,73,74,75,76,77,78,79)
    EM8(80,81,82,83,84,85,86,87) EM8(88,89,90,91,92,93,94,95)
    EX8(32,33,34,35,36,37,38,39) EX8(40,41,42,43,44,45,46,47)
    EX8(48,49,50,51,52,53,54,55) EX8(56,57,58,59,60,61,62,63)
    EX8(64,65,66,67,68,69,70,71) EX8(72,73,74,75,76,77,78,79)
    EX8(80,81,82,83,84,85,86,87) EX8(88,89,90,91,92,93,94,95)
    // p_1 = exp(u_1) * E[lane][START=62] (E[.][62] lives in v94)
    "v_mul_f32 v28, s61, v28\n\t"
    "v_exp_f32 v28, v28\n\t"
    "v_mul_f32 v26, v28, v94\n\t"
    // f_cur for t=2 from slot0 (v18)
    "v_mul_f32 v24, s61, v18\n\t"
    "v_exp_f32 v24, v24\n\t"
    // ---------------- main loop: 85 x 6 bodies (t=2..511) ----------------
    "1:\n\t"
    BODY("v18", "v19", "v24", "v25")
    BODY("v19", "v20", "v25", "v24")
    BODY("v20", "v21", "v24", "v25")
    BODY("v21", "v22", "v25", "v24")
    BODY("v22", "v23", "v24", "v25")
    BODY("v23", "v18", "v25", "v24")
    "s_sub_u32 s60, s60, 1\n\t"
    "s_cmp_lg_u32 s60, 0\n\t"
    "s_cbranch_scc1 1b\n\t"
    // ---------------- epilogue ----------------
    "v_mov_b32 %[pO], v26\n\t"
    "s_mov_b32 %[eO], s58\n\t"
    : [pO] "=&v"(p_out), [eO] "=&s"(esum_raw)
    : [fb] "s"(fb64), [ta] "v"(ta64), [voff] "v"(voff), [vmax] "v"(vmax)
    : "memory",
      "v10","v11","v12","v13","v14","v15","v16","v17","v18","v19",
      "v20","v21","v22","v23","v24","v25","v26","v27","v28","v29",
      "v32","v33","v34","v35","v36","v37","v38","v39",
      "v40","v41","v42","v43","v44","v45","v46","v47",
      "v48","v49","v50","v51","v52","v53","v54","v55",
      "v56","v57","v58","v59","v60","v61","v62","v63",
      "v64","v65","v66","v67","v68","v69","v70","v71",
      "v72","v73","v74","v75","v76","v77","v78","v79",
      "v80","v81","v82","v83","v84","v85","v86","v87",
      "v88","v89","v90","v91","v92","v93","v94","v95",
      "s40","s41","s42","s43","s44","s45","s46","s47",
      "s48","s49","s50","s51","s52","s53","s54","s55",
      "s56","s57","s58","s59","s60","s61");

  // forward score = log(sum_j p) + (esum_raw - 127*510)*ln2
  float bs = p_out;
  #pragma unroll
  for (int off = 32; off; off >>= 1) bs += __shfl_xor(bs, off);
  float fwd = __logf(bs) +
              (float)(esum_raw - 127 * 510) * 0.6931471805599453f;

  // ---- gold path score ----
  const int* tg = tags + b * TT;
  float gs = 0.0f;
  for (int tt = 1 + lane; tt < TT; tt += 64) {
    int tc = tg[tt];
    int tp = tg[tt - 1];
    gs += trans[tc * KK + tp]
        + feats[(size_t)b * TT * KK + (size_t)tt * KK + tc];
  }
  #pragma unroll
  for (int off = 32; off; off >>= 1) gs += __shfl_xor(gs, off);

  if (lane == 0) diff[b] = fwd - gs;
}

__global__ __launch_bounds__(1024) void reduce_mean_kernel(
    const float* __restrict__ diff, float* __restrict__ out)
{
  __shared__ float part[16];
  const int tid = threadIdx.x;
  float v = diff[tid];
  #pragma unroll
  for (int off = 32; off; off >>= 1) v += __shfl_xor(v, off);
  if ((tid & 63) == 0) part[tid >> 6] = v;
  __syncthreads();
  if (tid < 16) {
    float s = part[tid];
    #pragma unroll
    for (int off = 8; off; off >>= 1) s += __shfl_xor(s, off);
    if (tid == 0) out[0] = s * (1.0f / 1024.0f);
  }
}

extern "C" void kernel_launch(void* const* d_in, const int* in_sizes, int n_in,
                              void* d_out, int out_size, void* d_ws, size_t ws_size,
                              hipStream_t stream) {
  const float* feats = (const float*)d_in[0];
  const int*   tags  = (const int*)d_in[1];
  const float* trans = (const float*)d_in[2];
  float* out  = (float*)d_out;
  float* diff = (float*)d_ws;   // 1024 floats of scratch

  crf_forward_kernel<<<dim3(BB), dim3(64), 0, stream>>>(feats, tags, trans, diff);
  reduce_mean_kernel<<<dim3(1), dim3(1024), 0, stream>>>(diff, out);
}